// Round 1
// 1231.941 us; speedup vs baseline: 1.3240x; 1.3240x over previous
//
#include <hip/hip_runtime.h>

// Problem constants
#define BATCH 8
#define TT    512
#define DM    512
#define NH    8
#define DH    64
#define MM    (BATCH*TT)   // 4096 rows in the projection GEMMs

typedef __attribute__((ext_vector_type(8))) __bf16 bf16x8;
typedef __attribute__((ext_vector_type(4))) float  f32x4;
typedef __attribute__((ext_vector_type(8))) unsigned short u16x8;

union frag_cv { u16x8 u; bf16x8 b; };

// exact bf16->f32
__device__ __forceinline__ float b2f(unsigned short u) {
    union { unsigned int i; float f; } v;
    v.i = ((unsigned int)u) << 16;
    return v.f;
}
// f32->bf16 round-to-nearest-even (inputs finite)
__device__ __forceinline__ unsigned short f2b(float f) {
    union { float f; unsigned int u; } v; v.f = f;
    unsigned int r = v.u + 0x7FFFu + ((v.u >> 16) & 1u);
    return (unsigned short)(r >> 16);
}

// ---------------------------------------------------------------------------
// LDS-staged 64x64-tile GEMM: C = A @ B^T (+bias). K = N-per-weight = 512.
// MODE 0: fused QKV. A = x (f32) [4096x512]. Weight selected by blockIdx.x>>3
//         (0:Wq,1:Wk,2:Wv). Output scattered bf16 into [B,NH,T,DH]; Q scaled.
// MODE 1: out-proj. A = ctx (bf16 bits) [4096x512]; B = Wo; C = f32 out + bo.
// ---------------------------------------------------------------------------
template<int MODE>
__global__ __launch_bounds__(256) void gemm_tiled(const void* __restrict__ Ap,
                                                  const float* __restrict__ W0,
                                                  const float* __restrict__ W1,
                                                  const float* __restrict__ W2,
                                                  const float* __restrict__ b0,
                                                  const float* __restrict__ b1,
                                                  const float* __restrict__ b2,
                                                  unsigned short* __restrict__ O0,
                                                  unsigned short* __restrict__ O1,
                                                  unsigned short* __restrict__ O2,
                                                  float* __restrict__ Of) {
    // +8 pad: row stride 144B -> 2-way (free) bank aliasing instead of 16-way
    __shared__ __align__(16) unsigned short As[64][72];
    __shared__ __align__(16) unsigned short Bs[64][72];

    const int tid = threadIdx.x;
    const int m0b = blockIdx.y * 64;
    const int nb    = (MODE == 0) ? (int)(blockIdx.x >> 3) : 0;
    const int nbase = (MODE == 0) ? ((blockIdx.x & 7) * 64) : (blockIdx.x * 64);
    const float* W    = (MODE == 0) ? (nb == 0 ? W0 : (nb == 1 ? W1 : W2)) : W0;
    const float* bias = (MODE == 0) ? (nb == 0 ? b0 : (nb == 1 ? b1 : b2)) : b0;

    const int srow = tid >> 2;          // 0..63
    const int scol = (tid & 3) * 16;    // 0,16,32,48

    const int w = tid >> 6, lane = tid & 63;
    const int mw = (w & 1) * 32, nw = (w >> 1) * 32;
    const int mr = lane & 15, kq = (lane >> 4) * 8;

    f32x4 acc[2][2] = {};

    for (int kb = 0; kb < 512; kb += 64) {
        unsigned short av[16], bv[16];
        if (MODE == 0) {
            const float* ap = (const float*)Ap + (size_t)(m0b + srow) * 512 + kb + scol;
            f32x4 x0 = *(const f32x4*)(ap + 0);
            f32x4 x1 = *(const f32x4*)(ap + 4);
            f32x4 x2 = *(const f32x4*)(ap + 8);
            f32x4 x3 = *(const f32x4*)(ap + 12);
            #pragma unroll
            for (int e = 0; e < 4; ++e) {
                av[e]      = f2b(x0[e]);
                av[4 + e]  = f2b(x1[e]);
                av[8 + e]  = f2b(x2[e]);
                av[12 + e] = f2b(x3[e]);
            }
        } else {
            const unsigned short* ap = (const unsigned short*)Ap + (size_t)(m0b + srow) * 512 + kb + scol;
            *(u16x8*)&av[0] = *(const u16x8*)ap;
            *(u16x8*)&av[8] = *(const u16x8*)(ap + 8);
        }
        {
            const float* bp = W + (size_t)(nbase + srow) * 512 + kb + scol;
            f32x4 y0 = *(const f32x4*)(bp + 0);
            f32x4 y1 = *(const f32x4*)(bp + 4);
            f32x4 y2 = *(const f32x4*)(bp + 8);
            f32x4 y3 = *(const f32x4*)(bp + 12);
            #pragma unroll
            for (int e = 0; e < 4; ++e) {
                bv[e]      = f2b(y0[e]);
                bv[4 + e]  = f2b(y1[e]);
                bv[8 + e]  = f2b(y2[e]);
                bv[12 + e] = f2b(y3[e]);
            }
        }
        __syncthreads();   // previous tile's compute done
        *(u16x8*)&As[srow][scol]     = *(u16x8*)&av[0];
        *(u16x8*)&As[srow][scol + 8] = *(u16x8*)&av[8];
        *(u16x8*)&Bs[srow][scol]     = *(u16x8*)&bv[0];
        *(u16x8*)&Bs[srow][scol + 8] = *(u16x8*)&bv[8];
        __syncthreads();
        #pragma unroll
        for (int ko = 0; ko < 64; ko += 32) {
            frag_cv a0, a1, bb0, bb1;
            a0.u  = *(const u16x8*)&As[mw + mr][ko + kq];
            a1.u  = *(const u16x8*)&As[mw + 16 + mr][ko + kq];
            bb0.u = *(const u16x8*)&Bs[nw + mr][ko + kq];
            bb1.u = *(const u16x8*)&Bs[nw + 16 + mr][ko + kq];
            acc[0][0] = __builtin_amdgcn_mfma_f32_16x16x32_bf16(a0.b, bb0.b, acc[0][0], 0, 0, 0);
            acc[0][1] = __builtin_amdgcn_mfma_f32_16x16x32_bf16(a0.b, bb1.b, acc[0][1], 0, 0, 0);
            acc[1][0] = __builtin_amdgcn_mfma_f32_16x16x32_bf16(a1.b, bb0.b, acc[1][0], 0, 0, 0);
            acc[1][1] = __builtin_amdgcn_mfma_f32_16x16x32_bf16(a1.b, bb1.b, acc[1][1], 0, 0, 0);
        }
    }

    // C/D layout (verified m89/m91): col = lane&15, row = (lane>>4)*4 + reg
    const int rq = (lane >> 4) * 4;
    const int cc = lane & 15;
    const float scale = (MODE == 0 && nb == 0) ? 0.125f : 1.0f;
    unsigned short* Osel = (MODE == 0) ? (nb == 0 ? O0 : (nb == 1 ? O1 : O2)) : (unsigned short*)0;
    #pragma unroll
    for (int i = 0; i < 2; ++i) {
        #pragma unroll
        for (int j = 0; j < 2; ++j) {
            int gcol = nbase + nw + j * 16 + cc;   // 0..511 within this weight
            float bvv = bias[gcol];
            #pragma unroll
            for (int r2 = 0; r2 < 4; ++r2) {
                int grow = m0b + mw + i * 16 + rq + r2;
                float v = acc[i][j][r2] + bvv;
                if (MODE == 0) {
                    v *= scale;
                    int bb2 = grow >> 9, tt2 = grow & 511;
                    int hh = gcol >> 6, dd = gcol & 63;
                    Osel[((size_t)(bb2 * NH + hh) * TT + tt2) * DH + dd] = f2b(v);
                } else {
                    Of[(size_t)grow * 512 + gcol] = v;
                }
            }
        }
    }
}

// ---------------------------------------------------------------------------
// Attention: one block per (h, t-pair). 512 threads = one per s.
// score[b,s] = sum_d Q[b,h,t,d] * (K[b,h,s,d] + rel[t,s,h*64+d]); Q pre-scaled.
// Q is wave-uniform per (b,d) -> read via uniform (scalar) loads, converted
// with scalar shifts; inner MAC = v_lshl + v_add + v_fmac (SGPR multiplier).
// rel loaded exactly once per element (16 independent float4 / thread / t).
// ---------------------------------------------------------------------------
__global__ __launch_bounds__(512, 4) void attn_kernel(const unsigned short* __restrict__ Q,
                                                      const unsigned short* __restrict__ K,
                                                      const unsigned short* __restrict__ V,
                                                      const float* __restrict__ rel,
                                                      unsigned short* __restrict__ ctx) {
    __shared__ float sc[2][BATCH][TT];   // 32 KB

    const int h  = blockIdx.x >> 8;
    const int t0 = (blockIdx.x & 255) * 2;
    const int tid = threadIdx.x;

    // ---- scores: thread owns s = tid; two t's sequentially ----
    {
        const int s = tid;
        #pragma unroll 1
        for (int ti = 0; ti < 2; ++ti) {
            const int tt = t0 + ti;
            const float* rp = rel + ((size_t)tt * TT + s) * DM + h * DH;
            f32x4 r[16];
            #pragma unroll
            for (int c = 0; c < 16; ++c) r[c] = *(const f32x4*)(rp + c * 4);
            #pragma unroll 2
            for (int b = 0; b < 8; ++b) {
                const unsigned short* kp = K + ((size_t)(b * NH + h) * TT + s) * DH;
                const unsigned int*   qp = (const unsigned int*)(Q + ((size_t)(b * NH + h) * TT + tt) * DH);
                float a = 0.f;
                #pragma unroll
                for (int c = 0; c < 8; ++c) {
                    u16x8 kv = *(const u16x8*)(kp + c * 8);
                    #pragma unroll
                    for (int e = 0; e < 8; e += 2) {
                        unsigned int qw = qp[c * 4 + (e >> 1)];   // uniform -> s_load
                        float qlo = __uint_as_float(qw << 16);
                        float qhi = __uint_as_float(qw & 0xffff0000u);
                        int d = c * 8 + e;
                        a += (b2f(kv[e])     + r[d >> 2][d & 3])             * qlo;
                        a += (b2f(kv[e + 1]) + r[(d + 1) >> 2][(d + 1) & 3]) * qhi;
                    }
                }
                sc[ti][b][s] = a;
            }
        }
    }
    __syncthreads();

    const int w = tid >> 6, lane = tid & 63;

    // ---- softmax: wave w handles batch b = w, both t's ----
    #pragma unroll 1
    for (int ti = 0; ti < 2; ++ti) {
        float x[8], m = -1e30f;
        #pragma unroll
        for (int i = 0; i < 8; ++i) { x[i] = sc[ti][w][lane + 64 * i]; m = fmaxf(m, x[i]); }
        #pragma unroll
        for (int off = 32; off; off >>= 1) m = fmaxf(m, __shfl_xor(m, off));
        float sum = 0.f;
        #pragma unroll
        for (int i = 0; i < 8; ++i) { x[i] = __expf(x[i] - m); sum += x[i]; }
        #pragma unroll
        for (int off = 32; off; off >>= 1) sum += __shfl_xor(sum, off);
        float inv = 1.0f / sum;
        #pragma unroll
        for (int i = 0; i < 8; ++i) sc[ti][w][lane + 64 * i] = x[i] * inv;
    }
    __syncthreads();

    // ---- PV: wave w -> b = w. lane = (sg, j): s = sg + 8*it, d = j*8..j*8+7.
    // One u16x8 V row-chunk feeds 8 MACs x 2 t's; butterfly-reduce over sg. ----
    {
        const int b = w, sg = lane >> 3, j = lane & 7;
        const unsigned short* vbase = V + (size_t)(b * NH + h) * TT * DH;
        float a0[8] = {}, a1[8] = {};
        #pragma unroll 4
        for (int it = 0; it < 64; ++it) {
            int s = sg + it * 8;
            float p0 = sc[0][b][s];
            float p1 = sc[1][b][s];
            u16x8 vv = *(const u16x8*)(vbase + (size_t)s * DH + j * 8);
            #pragma unroll
            for (int e = 0; e < 8; ++e) {
                float vf = b2f(vv[e]);
                a0[e] += p0 * vf;
                a1[e] += p1 * vf;
            }
        }
        #pragma unroll
        for (int e = 0; e < 8; ++e) {
            a0[e] += __shfl_xor(a0[e], 8);
            a0[e] += __shfl_xor(a0[e], 16);
            a0[e] += __shfl_xor(a0[e], 32);
            a1[e] += __shfl_xor(a1[e], 8);
            a1[e] += __shfl_xor(a1[e], 16);
            a1[e] += __shfl_xor(a1[e], 32);
        }
        if (sg == 0) {
            u16x8 o0, o1;
            #pragma unroll
            for (int e = 0; e < 8; ++e) { o0[e] = f2b(a0[e]); o1[e] = f2b(a1[e]); }
            *(u16x8*)(ctx + ((size_t)b * TT + t0)     * DM + h * DH + j * 8) = o0;
            *(u16x8*)(ctx + ((size_t)b * TT + t0 + 1) * DM + h * DH + j * 8) = o1;
        }
    }
}

extern "C" void kernel_launch(void* const* d_in, const int* in_sizes, int n_in,
                              void* d_out, int out_size, void* d_ws, size_t ws_size,
                              hipStream_t stream) {
    const float* x    = (const float*)d_in[0];
    const float* rel  = (const float*)d_in[1];
    const float* Wq   = (const float*)d_in[2];
    const float* bq   = (const float*)d_in[3];
    const float* Wk   = (const float*)d_in[4];
    const float* bk   = (const float*)d_in[5];
    const float* Wv   = (const float*)d_in[6];
    const float* bv   = (const float*)d_in[7];
    const float* Wo   = (const float*)d_in[8];
    const float* bo   = (const float*)d_in[9];
    float* out = (float*)d_out;

    const size_t TENS = (size_t)BATCH * TT * DM;   // 2,097,152 elems
    // ws (12 MB): Q | K | ctx as bf16 bits. V (bf16, 4 MB) parks in d_out's
    // 8 MB float buffer; the final GEMM overwrites d_out after attn is done.
    unsigned short* Qw = (unsigned short*)d_ws;
    unsigned short* Kw = Qw + TENS;
    unsigned short* Cw = Kw + TENS;
    unsigned short* Vw = (unsigned short*)d_out;

    // Fused QKV projection: grid.x = 24 n-blocks (8 per weight), grid.y = 64 m-blocks.
    gemm_tiled<0><<<dim3(24, 64), 256, 0, stream>>>(x, Wq, Wk, Wv, bq, bk, bv,
                                                    Qw, Kw, Vw, nullptr);

    // Attention: one block per (h, t-pair)
    attn_kernel<<<NH * TT / 2, 512, 0, stream>>>(Qw, Kw, Vw, rel, Cw);

    // Output projection
    gemm_tiled<1><<<dim3(8, 64), 256, 0, stream>>>(Cw, Wo, nullptr, nullptr, bo,
                                                   nullptr, nullptr,
                                                   nullptr, nullptr, nullptr, out);
}